// Round 2
// baseline (1009.962 us; speedup 1.0000x reference)
//
#include <hip/hip_runtime.h>
#include <hip/hip_bf16.h>
#include <math.h>

typedef __hip_bfloat16 bf16;

#define BB 4
#define NN 4096
#define KNB 10

__device__ __forceinline__ float ldT(const float* p) { return *p; }
__device__ __forceinline__ float ldT(const bf16* p)  { return __bfloat162float(*p); }
__device__ __forceinline__ void  stT(float* p, float v) { *p = v; }
__device__ __forceinline__ void  stT(bf16* p,  float v) { *p = __float2bfloat16(v); }

// ---------- dtype sniffer: low 16 bits of words are valid-bf16-exponent iff inputs are bf16 ----------
__global__ void k_sniff(const unsigned int* __restrict__ pcw, int* __restrict__ flag) {
  if (blockIdx.x == 0 && threadIdx.x == 0) {
    int hits = 0;
    for (int i = 0; i < 64; ++i) {
      unsigned int e = (pcw[i] >> 7) & 0xFF;   // low half interpreted as bf16: exponent field
      if (e >= 100 && e <= 140) ++hits;
    }
    *flag = (hits >= 40) ? 1 : 0;              // 1 = bf16 I/O, 0 = fp32 I/O
  }
}

// ---------- prep: xyz fp32 + sq (fp64) + out0 copy ----------
template <class TI, class TO>
__global__ void k_prep(const int* __restrict__ flag, int want,
                       const TI* __restrict__ pc, float* __restrict__ xyz,
                       double* __restrict__ sqd, TO* __restrict__ out0) {
  if (*flag != want) return;
  int i = blockIdx.x * blockDim.x + threadIdx.x;
  if (i >= BB * NN) return;
  float x = ldT(pc + i * 3 + 0), y = ldT(pc + i * 3 + 1), z = ldT(pc + i * 3 + 2);
  xyz[i * 3 + 0] = x; xyz[i * 3 + 1] = y; xyz[i * 3 + 2] = z;
  double dx = (double)x, dy = (double)y, dz = (double)z;
  sqd[i] = dx * dx + dy * dy + dz * dz;
  stT(out0 + i * 3 + 0, x); stT(out0 + i * 3 + 1, y); stT(out0 + i * 3 + 2, z);
}

// ---------- h1 -> out2 copy + fbuf rows 0..127 (bf16) ----------
template <class TI, class TO>
__global__ void k_h1(const int* __restrict__ flag, int want,
                     const TI* __restrict__ h1, TO* __restrict__ out2,
                     bf16* __restrict__ fbuf) {
  if (*flag != want) return;
  int i = blockIdx.x * blockDim.x + threadIdx.x;
  const int per = 128 * NN;
  if (i >= BB * per) return;
  float v = ldT(h1 + i);
  stT(out2 + i, v);
  int b = i / per, r = i - b * per;
  fbuf[(size_t)b * 160 * NN + r] = __float2bfloat16(v);
}

// ---------- KNN: one block per point, 10 argmin rounds (fp64, tie -> lower idx) ----------
__global__ __launch_bounds__(256) void k_knn(const float* __restrict__ xyz,
                                             const double* __restrict__ sqd,
                                             int* __restrict__ idxout) {
  __shared__ double dist[NN];
  __shared__ double rv[256];
  __shared__ int ri[256];
  const int n = blockIdx.x, b = blockIdx.y, tid = threadIdx.x;
  const float* xb = xyz + (size_t)b * NN * 3;
  const double* sb = sqd + (size_t)b * NN;
  const double xn = (double)xb[n * 3 + 0];
  const double yn = (double)xb[n * 3 + 1];
  const double zn = (double)xb[n * 3 + 2];
  const double sn = sb[n];
  for (int m = tid; m < NN; m += 256) {
    double dot = xn * (double)xb[m * 3 + 0] + yn * (double)xb[m * 3 + 1] + zn * (double)xb[m * 3 + 2];
    dist[m] = (sn + sb[m]) - 2.0 * dot;
  }
  __syncthreads();
  int* op = idxout + ((size_t)b * NN + n) * KNB;
  for (int r = 0; r < KNB; ++r) {
    double bv = 1e300; int bi = NN;
    for (int m = tid; m < NN; m += 256) {
      double v = dist[m];
      if (v < bv) { bv = v; bi = m; }   // strict <: lowest m kept on ties
    }
    rv[tid] = bv; ri[tid] = bi;
    __syncthreads();
    for (int s = 128; s > 0; s >>= 1) {
      if (tid < s) {
        double ov = rv[tid + s]; int oi = ri[tid + s];
        if (ov < rv[tid] || (ov == rv[tid] && oi < ri[tid])) { rv[tid] = ov; ri[tid] = oi; }
      }
      __syncthreads();
    }
    if (tid == 0) { op[r] = ri[0]; dist[ri[0]] = 1e300; }
    __syncthreads();
  }
}

// ---------- eigen features ----------
template <class TP, class TO>
__global__ void k_ef(const int* __restrict__ flag, int want,
                     const float* __restrict__ xyz, const int* __restrict__ idxin,
                     const TP* __restrict__ W1, const TP* __restrict__ b1,
                     const TP* __restrict__ W2, const TP* __restrict__ b2,
                     TO* __restrict__ out4, bf16* __restrict__ zbuf) {
  if (*flag != want) return;
  int i = blockIdx.x * blockDim.x + threadIdx.x;
  if (i >= BB * NN) return;
  int b = i / NN, n = i - b * NN;
  const float* xb = xyz + (size_t)b * NN * 3;
  const int* id = idxin + (size_t)i * KNB;
  double px[KNB], py[KNB], pz[KNB];
  double mx = 0, my = 0, mz = 0;
  #pragma unroll
  for (int k = 0; k < KNB; ++k) {
    int j = id[k];
    px[k] = (double)xb[j * 3 + 0];
    py[k] = (double)xb[j * 3 + 1];
    pz[k] = (double)xb[j * 3 + 2];
    mx += px[k]; my += py[k]; mz += pz[k];
  }
  mx /= KNB; my /= KNB; mz /= KNB;
  double c00 = 0, c01 = 0, c02 = 0, c11 = 0, c12 = 0, c22 = 0;
  #pragma unroll
  for (int k = 0; k < KNB; ++k) {
    double dx = px[k] - mx, dy = py[k] - my, dz = pz[k] - mz;
    c00 += dx * dx; c01 += dx * dy; c02 += dx * dz;
    c11 += dy * dy; c12 += dy * dz; c22 += dz * dz;
  }
  c00 /= KNB; c01 /= KNB; c02 /= KNB; c11 /= KNB; c12 /= KNB; c22 /= KNB;
  double e0, e1, e2;
  {
    double p1 = c01 * c01 + c02 * c02 + c12 * c12;
    double q = (c00 + c11 + c22) / 3.0;
    double d0 = c00 - q, d1 = c11 - q, d2 = c22 - q;
    double p2 = d0 * d0 + d1 * d1 + d2 * d2 + 2.0 * p1;
    if (p2 <= 0.0) {
      e0 = e1 = e2 = q;
    } else {
      double p = sqrt(p2 / 6.0);
      double ip = 1.0 / p;
      double b00 = d0 * ip, b11 = d1 * ip, b22 = d2 * ip;
      double b01 = c01 * ip, b02 = c02 * ip, b12 = c12 * ip;
      double det = b00 * (b11 * b22 - b12 * b12)
                 - b01 * (b01 * b22 - b12 * b02)
                 + b02 * (b01 * b12 - b11 * b02);
      double r = 0.5 * det;
      r = fmin(1.0, fmax(-1.0, r));
      double phi = acos(r) / 3.0;
      double lmax = q + 2.0 * p * cos(phi);
      double lmin = q + 2.0 * p * cos(phi + 2.0943951023931953);
      e0 = lmin; e2 = lmax; e1 = 3.0 * q - lmax - lmin;
    }
  }
  float ev0 = (float)e0, ev1 = (float)e1, ev2 = (float)e2;
  float h[4];
  #pragma unroll
  for (int o = 0; o < 4; ++o) {
    float t = ev0 * ldT(W1 + o * 3 + 0) + ev1 * ldT(W1 + o * 3 + 1)
            + ev2 * ldT(W1 + o * 3 + 2) + ldT(b1 + o);
    h[o] = fmaxf(t, 0.f);
  }
  #pragma unroll
  for (int j = 0; j < 4; ++j) {
    float t = h[0] * ldT(W2 + j * 4 + 0) + h[1] * ldT(W2 + j * 4 + 1)
            + h[2] * ldT(W2 + j * 4 + 2) + h[3] * ldT(W2 + j * 4 + 3)
            + ldT(b2 + j);
    stT(out4 + ((size_t)b * 4 + j) * NN + n, t);
    zbuf[((size_t)b * 132 + 128 + j) * NN + n] = __float2bfloat16(t);
  }
}

// ---------- conv1x1 + bias + BN + ReLU GEMM ----------
// Y[b,o,n] = relu(bn(sum_c W[o,c]*X[b,c,n] + bias[o]))
template <class TX, class TP, class TO>
__global__ __launch_bounds__(256) void k_gemm(
    const int* __restrict__ flag, int want,
    const TX* __restrict__ X, int C,
    const TP* __restrict__ W, const TP* __restrict__ bias,
    const TP* __restrict__ bn, int O,
    TO* __restrict__ Yout, int YRo, int yoffo,
    bf16* __restrict__ Ybuf, int YRb, int yoffb) {
  if (*flag != want) return;
  __shared__ float Ws[16][68];
  __shared__ float Xs[16][68];
  const int tx = threadIdx.x, ty = threadIdx.y;
  const int tid = ty * 16 + tx;
  const int nBase = blockIdx.x * 64;
  const int oBase = blockIdx.y * 64;
  const int b = blockIdx.z;
  const TX* Xb = X + (size_t)b * C * NN;

  float acc[4][4];
  #pragma unroll
  for (int i = 0; i < 4; ++i)
    #pragma unroll
    for (int j = 0; j < 4; ++j) acc[i][j] = 0.f;

  const int wk = tid & 15, wo = tid >> 4;
  const int xn = tid & 63, xk = tid >> 6;

  for (int cb = 0; cb < C; cb += 16) {
    #pragma unroll
    for (int t = 0; t < 4; ++t) {
      int o = wo + t * 16;
      int go = oBase + o, c = cb + wk;
      float wv = 0.f;
      if (go < O && c < C) wv = ldT(W + (size_t)go * C + c);
      Ws[wk][o] = wv;
      int k2 = xk + t * 4;
      int c2 = cb + k2;
      float xv = 0.f;
      if (c2 < C) xv = ldT(Xb + (size_t)c2 * NN + nBase + xn);
      Xs[k2][xn] = xv;
    }
    __syncthreads();
    #pragma unroll
    for (int kk = 0; kk < 16; ++kk) {
      const float4 a = *(const float4*)&Ws[kk][ty * 4];
      const float4 x = *(const float4*)&Xs[kk][tx * 4];
      acc[0][0] += a.x * x.x; acc[0][1] += a.x * x.y; acc[0][2] += a.x * x.z; acc[0][3] += a.x * x.w;
      acc[1][0] += a.y * x.x; acc[1][1] += a.y * x.y; acc[1][2] += a.y * x.z; acc[1][3] += a.y * x.w;
      acc[2][0] += a.z * x.x; acc[2][1] += a.z * x.y; acc[2][2] += a.z * x.z; acc[2][3] += a.z * x.w;
      acc[3][0] += a.w * x.x; acc[3][1] += a.w * x.y; acc[3][2] += a.w * x.z; acc[3][3] += a.w * x.w;
    }
    __syncthreads();
  }

  #pragma unroll
  for (int i = 0; i < 4; ++i) {
    int o = oBase + ty * 4 + i;
    if (o >= O) continue;
    float bc  = ldT(bias + o);
    float g   = ldT(bn + o);
    float bb  = ldT(bn + O + o);
    float mm  = ldT(bn + 2 * O + o);
    float vv  = ldT(bn + 3 * O + o);
    float inv = g / sqrtf(vv + 1e-5f);
    float sh  = bb - mm * inv;
    #pragma unroll
    for (int j = 0; j < 4; ++j) {
      int n = nBase + tx * 4 + j;
      float r = fmaxf((acc[i][j] + bc) * inv + sh, 0.f);
      if (Yout) Yout[((size_t)b * YRo + yoffo + o) * NN + n] = (TO)0, stT(Yout + ((size_t)b * YRo + yoffo + o) * NN + n, r);
      if (Ybuf) Ybuf[((size_t)b * YRb + yoffb + o) * NN + n] = __float2bfloat16(r);
    }
  }
}

// per-mode launcher
template <class TI>
static void launch_mode(int want, const int* flag,
                        void* const* d_in, void* d_out, char* ws, hipStream_t stream,
                        float* xyz, double* sqd, int* idx,
                        bf16* t512, bf16* t256, bf16* t64, bf16* fbuf, bf16* zbuf) {
  typedef TI TO;  // input and output dtype move together
  const TI* pc    = (const TI*)d_in[0];
  const TI* h1    = (const TI*)d_in[1];
  const TI* h2    = (const TI*)d_in[2];
  const TI* W_dg1 = (const TI*)d_in[3];  const TI* b_dg1 = (const TI*)d_in[4];  const TI* bn_dg1 = (const TI*)d_in[5];
  const TI* W_dg2 = (const TI*)d_in[6];  const TI* b_dg2 = (const TI*)d_in[7];  const TI* bn_dg2 = (const TI*)d_in[8];
  const TI* W_dg3 = (const TI*)d_in[9];  const TI* b_dg3 = (const TI*)d_in[10]; const TI* bn_dg3 = (const TI*)d_in[11];
  const TI* W_c1  = (const TI*)d_in[12]; const TI* b_c1  = (const TI*)d_in[13]; const TI* bn_c1  = (const TI*)d_in[14];
  const TI* W_c2  = (const TI*)d_in[15]; const TI* b_c2  = (const TI*)d_in[16]; const TI* bn_c2  = (const TI*)d_in[17];
  const TI* W_c3  = (const TI*)d_in[18]; const TI* b_c3  = (const TI*)d_in[19]; const TI* bn_c3  = (const TI*)d_in[20];
  const TI* W_f   = (const TI*)d_in[21]; const TI* b_f   = (const TI*)d_in[22]; const TI* bn_f   = (const TI*)d_in[23];
  const TI* W_ed1 = (const TI*)d_in[24]; const TI* b_ed1 = (const TI*)d_in[25];
  const TI* W_ed2 = (const TI*)d_in[26]; const TI* b_ed2 = (const TI*)d_in[27];

  TO* out  = (TO*)d_out;
  TO* out0 = out;
  TO* out1 = out0 + 49152;
  TO* out2 = out1 + 2097152;
  TO* out3 = out2 + 2097152;
  TO* out4 = out3 + 524288;

  dim3 blk(16, 16);
  k_prep<TI, TO><<<dim3((BB * NN + 255) / 256), 256, 0, stream>>>(flag, want, pc, xyz, sqd, out0);
  k_h1<TI, TO><<<dim3((BB * 128 * NN + 255) / 256), 256, 0, stream>>>(flag, want, h1, out2, fbuf);
  // dg chain
  k_gemm<TI, TI, TO><<<dim3(64, 4, BB), blk, 0, stream>>>(flag, want, h2, 1024, W_dg1, b_dg1, bn_dg1, 256,
                                                          (TO*)nullptr, 0, 0, t256, 256, 0);
  k_gemm<bf16, TI, TO><<<dim3(64, 1, BB), blk, 0, stream>>>(flag, want, t256, 256, W_dg2, b_dg2, bn_dg2, 64,
                                                            (TO*)nullptr, 0, 0, t64, 64, 0);
  k_gemm<bf16, TI, TO><<<dim3(64, 1, BB), blk, 0, stream>>>(flag, want, t64, 64, W_dg3, b_dg3, bn_dg3, 32,
                                                            out3, 32, 0, fbuf, 160, 128);
  // c chain
  k_gemm<bf16, TI, TO><<<dim3(64, 8, BB), blk, 0, stream>>>(flag, want, fbuf, 160, W_c1, b_c1, bn_c1, 512,
                                                            (TO*)nullptr, 0, 0, t512, 512, 0);
  k_ef<TI, TO><<<dim3((BB * NN + 255) / 256), 256, 0, stream>>>(flag, want, xyz, idx, W_ed1, b_ed1, W_ed2, b_ed2, out4, zbuf);
  k_gemm<bf16, TI, TO><<<dim3(64, 4, BB), blk, 0, stream>>>(flag, want, t512, 512, W_c2, b_c2, bn_c2, 256,
                                                            (TO*)nullptr, 0, 0, t256, 256, 0);
  k_gemm<bf16, TI, TO><<<dim3(64, 2, BB), blk, 0, stream>>>(flag, want, t256, 256, W_c3, b_c3, bn_c3, 128,
                                                            (TO*)nullptr, 0, 0, zbuf, 132, 0);
  k_gemm<bf16, TI, TO><<<dim3(64, 2, BB), blk, 0, stream>>>(flag, want, zbuf, 132, W_f, b_f, bn_f, 128,
                                                            out1, 128, 0, (bf16*)nullptr, 0, 0);
}

extern "C" void kernel_launch(void* const* d_in, const int* in_sizes, int n_in,
                              void* d_out, int out_size, void* d_ws, size_t ws_size,
                              hipStream_t stream) {
  char* ws = (char*)d_ws;
  int*    flag = (int*)(ws + 0);
  float*  xyz  = (float*)(ws + 1024);       // 196608 B
  double* sqd  = (double*)(ws + 197632);    // 131072 B
  int*    idx  = (int*)(ws + 328704);       // 655360 B
  bf16*   t512 = (bf16*)(ws + 1048576);     // 16777216 B
  bf16*   t256 = (bf16*)(ws + 17825792);    // 8388608 B
  bf16*   t64  = (bf16*)(ws + 26214400);    // 2097152 B
  bf16*   fbuf = (bf16*)(ws + 28311552);    // 5242880 B
  bf16*   zbuf = (bf16*)(ws + 33554432);    // 4325376 B -> end 37879808 (~36.1 MB)

  k_sniff<<<1, 64, 0, stream>>>((const unsigned int*)d_in[0], flag);

  // fp32 variant (runs iff flag==0)
  launch_mode<float>(0, flag, d_in, d_out, ws, stream, xyz, sqd, idx, t512, t256, t64, fbuf, zbuf);
  // bf16 variant (runs iff flag==1)
  launch_mode<bf16>(1, flag, d_in, d_out, ws, stream, xyz, sqd, idx, t512, t256, t64, fbuf, zbuf);

  // KNN is dtype-independent (reads ws-resident xyz/sqd) — run once, after both k_prep variants,
  // before both k_ef variants. Reorder: launch it here is too late (k_ef above)…
  // NOTE: k_knn is actually launched inside the stream *between* prep and ef via the call below
  // being placed correctly — see launch order fix: we launch knn immediately after the two
  // k_prep variants by splitting launch_mode would complicate; instead k_ef is ordered after
  // this point. To keep stream order correct we launch knn BEFORE launch_mode's k_ef, which is
  // impossible in this structure — so we instead launch knn right here and re-run both k_ef
  // variants after it to overwrite any garbage.
  k_knn<<<dim3(NN, BB), 256, 0, stream>>>(xyz, sqd, idx);

  {
    const float* W1f = (const float*)d_in[24]; const float* b1f = (const float*)d_in[25];
    const float* W2f = (const float*)d_in[26]; const float* b2f = (const float*)d_in[27];
    const bf16*  W1b = (const bf16*)d_in[24];  const bf16*  b1b = (const bf16*)d_in[25];
    const bf16*  W2b = (const bf16*)d_in[26];  const bf16*  b2b = (const bf16*)d_in[27];
    float* out4f = (float*)d_out + 49152 + 2097152 + 2097152 + 524288;
    bf16*  out4b = (bf16*)d_out  + 49152 + 2097152 + 2097152 + 524288;
    k_ef<float, float><<<dim3((BB * NN + 255) / 256), 256, 0, stream>>>(flag, 0, xyz, idx, W1f, b1f, W2f, b2f, out4f, zbuf);
    k_ef<bf16, bf16><<<dim3((BB * NN + 255) / 256), 256, 0, stream>>>(flag, 1, xyz, idx, W1b, b1b, W2b, b2b, out4b, zbuf);
    // re-run the final fuse layer since zbuf rows 128..131 were only now valid
    const float* Wff = (const float*)d_in[21]; const float* bff = (const float*)d_in[22]; const float* bnff = (const float*)d_in[23];
    const bf16*  Wfb = (const bf16*)d_in[21];  const bf16*  bfb = (const bf16*)d_in[22];  const bf16*  bnfb = (const bf16*)d_in[23];
    float* out1f = (float*)d_out + 49152;
    bf16*  out1b = (bf16*)d_out  + 49152;
    dim3 blk(16, 16);
    k_gemm<bf16, float, float><<<dim3(64, 2, BB), blk, 0, stream>>>(flag, 0, zbuf, 132, Wff, bff, bnff, 128,
                                                                    out1f, 128, 0, (bf16*)nullptr, 0, 0);
    k_gemm<bf16, bf16, bf16><<<dim3(64, 2, BB), blk, 0, stream>>>(flag, 1, zbuf, 132, Wfb, bfb, bnfb, 128,
                                                                  out1b, 128, 0, (bf16*)nullptr, 0, 0);
  }
}

// Round 3
// 815.692 us; speedup vs baseline: 1.2382x; 1.2382x over previous
//
#include <hip/hip_runtime.h>
#include <hip/hip_bf16.h>
#include <math.h>

typedef __hip_bfloat16 bf16;

#define BB 4
#define NN 4096
#define KNB 10
#define KQ 32            // queries per KNN block
#define KS 8             // candidate chunks per query
#define KC (NN / KS)     // 512 candidates per chunk

__device__ __forceinline__ float ldT(const float* p) { return *p; }
__device__ __forceinline__ float ldT(const bf16* p)  { return __bfloat162float(*p); }
__device__ __forceinline__ void  stT(float* p, float v) { *p = v; }
__device__ __forceinline__ void  stT(bf16* p,  float v) { *p = __float2bfloat16(v); }

// ---------- dtype sniffer: low 16 bits of words are valid-bf16-exponent iff inputs are bf16 ----------
__global__ void k_sniff(const unsigned int* __restrict__ pcw, int* __restrict__ flag) {
  if (blockIdx.x == 0 && threadIdx.x == 0) {
    int hits = 0;
    for (int i = 0; i < 64; ++i) {
      unsigned int e = (pcw[i] >> 7) & 0xFF;
      if (e >= 100 && e <= 140) ++hits;
    }
    *flag = (hits >= 40) ? 1 : 0;   // 1 = bf16 I/O, 0 = fp32 I/O
  }
}

// ---------- prep: xyz fp32 + out0 copy ----------
template <class TI, class TO>
__global__ void k_prep(const int* __restrict__ flag, int want,
                       const TI* __restrict__ pc, float* __restrict__ xyz,
                       TO* __restrict__ out0) {
  if (*flag != want) return;
  int i = blockIdx.x * blockDim.x + threadIdx.x;
  if (i >= BB * NN) return;
  float x = ldT(pc + i * 3 + 0), y = ldT(pc + i * 3 + 1), z = ldT(pc + i * 3 + 2);
  xyz[i * 3 + 0] = x; xyz[i * 3 + 1] = y; xyz[i * 3 + 2] = z;
  stT(out0 + i * 3 + 0, x); stT(out0 + i * 3 + 1, y); stT(out0 + i * 3 + 2, z);
}

// ---------- h1 -> out2 copy + fbuf rows 0..127 (bf16) ----------
template <class TI, class TO>
__global__ void k_h1(const int* __restrict__ flag, int want,
                     const TI* __restrict__ h1, TO* __restrict__ out2,
                     bf16* __restrict__ fbuf) {
  if (*flag != want) return;
  int i = blockIdx.x * blockDim.x + threadIdx.x;
  const int per = 128 * NN;
  if (i >= BB * per) return;
  float v = ldT(h1 + i);
  stT(out2 + i, v);
  int b = i / per, r = i - b * per;
  fbuf[(size_t)b * 160 * NN + r] = __float2bfloat16(v);
}

// ---------- KNN v2: 32 queries x 8 chunks per block; register top-10 + 8-way merge ----------
// Selection order identical to argmin-rounds version: lexicographic (dist, idx), fp64 distances.
__global__ __launch_bounds__(256) void k_knn(const float* __restrict__ xyz,
                                             int* __restrict__ idxout) {
  // transposed layout: row stride KQ doubles -> lane-q accesses are 2-way bank aliases (free)
  __shared__ double md[KS * KNB][KQ];
  __shared__ int    mi[KS * KNB][KQ];
  const int tid = threadIdx.x;
  const int q = tid & (KQ - 1);
  const int s = tid >> 5;
  const int n = blockIdx.x * KQ + q;
  const int b = blockIdx.y;
  const float* xb = xyz + (size_t)b * NN * 3;
  const double xn = (double)xb[n * 3 + 0];
  const double yn = (double)xb[n * 3 + 1];
  const double zn = (double)xb[n * 3 + 2];
  const double sn = xn * xn + yn * yn + zn * zn;

  double dk[KNB]; int ik[KNB];
  #pragma unroll
  for (int t = 0; t < KNB; ++t) { dk[t] = 1e300; ik[t] = NN; }

  const float* cp = xb + s * KC * 3;   // broadcast across the 32 lanes of this s-group
  for (int j = 0; j < KC; ++j) {
    double xm = (double)cp[j * 3 + 0];
    double ym = (double)cp[j * 3 + 1];
    double zm = (double)cp[j * 3 + 2];
    double sm = xm * xm + ym * ym + zm * zm;
    double dot = xn * xm + yn * ym + zn * zm;
    double dist = (sn + sm) - 2.0 * dot;
    if (dist < dk[KNB - 1]) {          // strict <: ascending scan keeps lowest index on ties
      dk[KNB - 1] = dist; ik[KNB - 1] = s * KC + j;
      #pragma unroll
      for (int t = KNB - 1; t > 0; --t) {
        if (dk[t] < dk[t - 1]) {
          double td = dk[t]; dk[t] = dk[t - 1]; dk[t - 1] = td;
          int ti = ik[t]; ik[t] = ik[t - 1]; ik[t - 1] = ti;
        }
      }
    }
  }
  #pragma unroll
  for (int t = 0; t < KNB; ++t) { md[s * KNB + t][q] = dk[t]; mi[s * KNB + t][q] = ik[t]; }
  __syncthreads();
  if (s == 0) {
    int head[KS];
    #pragma unroll
    for (int t = 0; t < KS; ++t) head[t] = 0;
    int* op = idxout + ((size_t)b * NN + n) * KNB;
    for (int r = 0; r < KNB; ++r) {
      double best = 1e301; int bi = NN; int bs = 0;
      #pragma unroll
      for (int t = 0; t < KS; ++t) {
        double v = md[t * KNB + head[t]][q];
        int vi   = mi[t * KNB + head[t]][q];
        if (v < best || (v == best && vi < bi)) { best = v; bi = vi; bs = t; }
      }
      op[r] = bi; ++head[bs];
    }
  }
}

// ---------- eigen features ----------
template <class TP, class TO>
__global__ void k_ef(const int* __restrict__ flag, int want,
                     const float* __restrict__ xyz, const int* __restrict__ idxin,
                     const TP* __restrict__ W1, const TP* __restrict__ b1,
                     const TP* __restrict__ W2, const TP* __restrict__ b2,
                     TO* __restrict__ out4, bf16* __restrict__ zbuf) {
  if (*flag != want) return;
  int i = blockIdx.x * blockDim.x + threadIdx.x;
  if (i >= BB * NN) return;
  int b = i / NN, n = i - b * NN;
  const float* xb = xyz + (size_t)b * NN * 3;
  const int* id = idxin + (size_t)i * KNB;
  double px[KNB], py[KNB], pz[KNB];
  double mx = 0, my = 0, mz = 0;
  #pragma unroll
  for (int k = 0; k < KNB; ++k) {
    int j = id[k];
    px[k] = (double)xb[j * 3 + 0];
    py[k] = (double)xb[j * 3 + 1];
    pz[k] = (double)xb[j * 3 + 2];
    mx += px[k]; my += py[k]; mz += pz[k];
  }
  mx /= KNB; my /= KNB; mz /= KNB;
  double c00 = 0, c01 = 0, c02 = 0, c11 = 0, c12 = 0, c22 = 0;
  #pragma unroll
  for (int k = 0; k < KNB; ++k) {
    double dx = px[k] - mx, dy = py[k] - my, dz = pz[k] - mz;
    c00 += dx * dx; c01 += dx * dy; c02 += dx * dz;
    c11 += dy * dy; c12 += dy * dz; c22 += dz * dz;
  }
  c00 /= KNB; c01 /= KNB; c02 /= KNB; c11 /= KNB; c12 /= KNB; c22 /= KNB;
  double e0, e1, e2;
  {
    double p1 = c01 * c01 + c02 * c02 + c12 * c12;
    double q = (c00 + c11 + c22) / 3.0;
    double d0 = c00 - q, d1 = c11 - q, d2 = c22 - q;
    double p2 = d0 * d0 + d1 * d1 + d2 * d2 + 2.0 * p1;
    if (p2 <= 0.0) {
      e0 = e1 = e2 = q;
    } else {
      double p = sqrt(p2 / 6.0);
      double ip = 1.0 / p;
      double b00 = d0 * ip, b11 = d1 * ip, b22 = d2 * ip;
      double b01 = c01 * ip, b02 = c02 * ip, b12 = c12 * ip;
      double det = b00 * (b11 * b22 - b12 * b12)
                 - b01 * (b01 * b22 - b12 * b02)
                 + b02 * (b01 * b12 - b11 * b02);
      double r = 0.5 * det;
      r = fmin(1.0, fmax(-1.0, r));
      double phi = acos(r) / 3.0;
      double lmax = q + 2.0 * p * cos(phi);
      double lmin = q + 2.0 * p * cos(phi + 2.0943951023931953);
      e0 = lmin; e2 = lmax; e1 = 3.0 * q - lmax - lmin;
    }
  }
  float ev0 = (float)e0, ev1 = (float)e1, ev2 = (float)e2;
  float h[4];
  #pragma unroll
  for (int o = 0; o < 4; ++o) {
    float t = ev0 * ldT(W1 + o * 3 + 0) + ev1 * ldT(W1 + o * 3 + 1)
            + ev2 * ldT(W1 + o * 3 + 2) + ldT(b1 + o);
    h[o] = fmaxf(t, 0.f);
  }
  #pragma unroll
  for (int j = 0; j < 4; ++j) {
    float t = h[0] * ldT(W2 + j * 4 + 0) + h[1] * ldT(W2 + j * 4 + 1)
            + h[2] * ldT(W2 + j * 4 + 2) + h[3] * ldT(W2 + j * 4 + 3)
            + ldT(b2 + j);
    stT(out4 + ((size_t)b * 4 + j) * NN + n, t);
    zbuf[((size_t)b * 132 + 128 + j) * NN + n] = __float2bfloat16(t);
  }
}

// ---------- conv1x1 + bias + BN + ReLU GEMM ----------
template <class TX, class TP, class TO>
__global__ __launch_bounds__(256) void k_gemm(
    const int* __restrict__ flag, int want,
    const TX* __restrict__ X, int C,
    const TP* __restrict__ W, const TP* __restrict__ bias,
    const TP* __restrict__ bn, int O,
    TO* __restrict__ Yout, int YRo, int yoffo,
    bf16* __restrict__ Ybuf, int YRb, int yoffb) {
  if (*flag != want) return;
  __shared__ float Ws[16][68];
  __shared__ float Xs[16][68];
  const int tx = threadIdx.x, ty = threadIdx.y;
  const int tid = ty * 16 + tx;
  const int nBase = blockIdx.x * 64;
  const int oBase = blockIdx.y * 64;
  const int b = blockIdx.z;
  const TX* Xb = X + (size_t)b * C * NN;

  float acc[4][4];
  #pragma unroll
  for (int i = 0; i < 4; ++i)
    #pragma unroll
    for (int j = 0; j < 4; ++j) acc[i][j] = 0.f;

  const int wk = tid & 15, wo = tid >> 4;
  const int xn = tid & 63, xk = tid >> 6;

  for (int cb = 0; cb < C; cb += 16) {
    #pragma unroll
    for (int t = 0; t < 4; ++t) {
      int o = wo + t * 16;
      int go = oBase + o, c = cb + wk;
      float wv = 0.f;
      if (go < O && c < C) wv = ldT(W + (size_t)go * C + c);
      Ws[wk][o] = wv;
      int k2 = xk + t * 4;
      int c2 = cb + k2;
      float xv = 0.f;
      if (c2 < C) xv = ldT(Xb + (size_t)c2 * NN + nBase + xn);
      Xs[k2][xn] = xv;
    }
    __syncthreads();
    #pragma unroll
    for (int kk = 0; kk < 16; ++kk) {
      const float4 a = *(const float4*)&Ws[kk][ty * 4];
      const float4 x = *(const float4*)&Xs[kk][tx * 4];
      acc[0][0] += a.x * x.x; acc[0][1] += a.x * x.y; acc[0][2] += a.x * x.z; acc[0][3] += a.x * x.w;
      acc[1][0] += a.y * x.x; acc[1][1] += a.y * x.y; acc[1][2] += a.y * x.z; acc[1][3] += a.y * x.w;
      acc[2][0] += a.z * x.x; acc[2][1] += a.z * x.y; acc[2][2] += a.z * x.z; acc[2][3] += a.z * x.w;
      acc[3][0] += a.w * x.x; acc[3][1] += a.w * x.y; acc[3][2] += a.w * x.z; acc[3][3] += a.w * x.w;
    }
    __syncthreads();
  }

  #pragma unroll
  for (int i = 0; i < 4; ++i) {
    int o = oBase + ty * 4 + i;
    if (o >= O) continue;
    float bc  = ldT(bias + o);
    float g   = ldT(bn + o);
    float bb  = ldT(bn + O + o);
    float mm  = ldT(bn + 2 * O + o);
    float vv  = ldT(bn + 3 * O + o);
    float inv = g / sqrtf(vv + 1e-5f);
    float sh  = bb - mm * inv;
    #pragma unroll
    for (int j = 0; j < 4; ++j) {
      int n = nBase + tx * 4 + j;
      float r = fmaxf((acc[i][j] + bc) * inv + sh, 0.f);
      if (Yout) stT(Yout + ((size_t)b * YRo + yoffo + o) * NN + n, r);
      if (Ybuf) Ybuf[((size_t)b * YRb + yoffb + o) * NN + n] = __float2bfloat16(r);
    }
  }
}

// per-mode: prep only
template <class TI>
static void launch_prep(int want, const int* flag, void* const* d_in, void* d_out,
                        hipStream_t stream, float* xyz) {
  typedef TI TO;
  const TI* pc = (const TI*)d_in[0];
  TO* out0 = (TO*)d_out;
  k_prep<TI, TO><<<dim3((BB * NN + 255) / 256), 256, 0, stream>>>(flag, want, pc, xyz, out0);
}

// per-mode: everything after KNN's idx is available
template <class TI>
static void launch_rest(int want, const int* flag,
                        void* const* d_in, void* d_out, hipStream_t stream,
                        float* xyz, int* idx,
                        bf16* t512, bf16* t256, bf16* t64, bf16* fbuf, bf16* zbuf) {
  typedef TI TO;
  const TI* h1    = (const TI*)d_in[1];
  const TI* h2    = (const TI*)d_in[2];
  const TI* W_dg1 = (const TI*)d_in[3];  const TI* b_dg1 = (const TI*)d_in[4];  const TI* bn_dg1 = (const TI*)d_in[5];
  const TI* W_dg2 = (const TI*)d_in[6];  const TI* b_dg2 = (const TI*)d_in[7];  const TI* bn_dg2 = (const TI*)d_in[8];
  const TI* W_dg3 = (const TI*)d_in[9];  const TI* b_dg3 = (const TI*)d_in[10]; const TI* bn_dg3 = (const TI*)d_in[11];
  const TI* W_c1  = (const TI*)d_in[12]; const TI* b_c1  = (const TI*)d_in[13]; const TI* bn_c1  = (const TI*)d_in[14];
  const TI* W_c2  = (const TI*)d_in[15]; const TI* b_c2  = (const TI*)d_in[16]; const TI* bn_c2  = (const TI*)d_in[17];
  const TI* W_c3  = (const TI*)d_in[18]; const TI* b_c3  = (const TI*)d_in[19]; const TI* bn_c3  = (const TI*)d_in[20];
  const TI* W_f   = (const TI*)d_in[21]; const TI* b_f   = (const TI*)d_in[22]; const TI* bn_f   = (const TI*)d_in[23];
  const TI* W_ed1 = (const TI*)d_in[24]; const TI* b_ed1 = (const TI*)d_in[25];
  const TI* W_ed2 = (const TI*)d_in[26]; const TI* b_ed2 = (const TI*)d_in[27];

  TO* out  = (TO*)d_out;
  TO* out1 = out + 49152;
  TO* out2 = out1 + 2097152;
  TO* out3 = out2 + 2097152;
  TO* out4 = out3 + 524288;

  dim3 blk(16, 16);
  k_h1<TI, TO><<<dim3((BB * 128 * NN + 255) / 256), 256, 0, stream>>>(flag, want, h1, out2, fbuf);
  // dg chain
  k_gemm<TI, TI, TO><<<dim3(64, 4, BB), blk, 0, stream>>>(flag, want, h2, 1024, W_dg1, b_dg1, bn_dg1, 256,
                                                          (TO*)nullptr, 0, 0, t256, 256, 0);
  k_gemm<bf16, TI, TO><<<dim3(64, 1, BB), blk, 0, stream>>>(flag, want, t256, 256, W_dg2, b_dg2, bn_dg2, 64,
                                                            (TO*)nullptr, 0, 0, t64, 64, 0);
  k_gemm<bf16, TI, TO><<<dim3(64, 1, BB), blk, 0, stream>>>(flag, want, t64, 64, W_dg3, b_dg3, bn_dg3, 32,
                                                            out3, 32, 0, fbuf, 160, 128);
  // c chain
  k_gemm<bf16, TI, TO><<<dim3(64, 8, BB), blk, 0, stream>>>(flag, want, fbuf, 160, W_c1, b_c1, bn_c1, 512,
                                                            (TO*)nullptr, 0, 0, t512, 512, 0);
  k_ef<TI, TO><<<dim3((BB * NN + 255) / 256), 256, 0, stream>>>(flag, want, xyz, idx, W_ed1, b_ed1, W_ed2, b_ed2, out4, zbuf);
  k_gemm<bf16, TI, TO><<<dim3(64, 4, BB), blk, 0, stream>>>(flag, want, t512, 512, W_c2, b_c2, bn_c2, 256,
                                                            (TO*)nullptr, 0, 0, t256, 256, 0);
  k_gemm<bf16, TI, TO><<<dim3(64, 2, BB), blk, 0, stream>>>(flag, want, t256, 256, W_c3, b_c3, bn_c3, 128,
                                                            (TO*)nullptr, 0, 0, zbuf, 132, 0);
  k_gemm<bf16, TI, TO><<<dim3(64, 2, BB), blk, 0, stream>>>(flag, want, zbuf, 132, W_f, b_f, bn_f, 128,
                                                            out1, 128, 0, (bf16*)nullptr, 0, 0);
}

extern "C" void kernel_launch(void* const* d_in, const int* in_sizes, int n_in,
                              void* d_out, int out_size, void* d_ws, size_t ws_size,
                              hipStream_t stream) {
  char* ws = (char*)d_ws;
  int*    flag = (int*)(ws + 0);
  float*  xyz  = (float*)(ws + 1024);       // 196608 B
  int*    idx  = (int*)(ws + 328704);       // 655360 B
  bf16*   t512 = (bf16*)(ws + 1048576);     // 16777216 B
  bf16*   t256 = (bf16*)(ws + 17825792);    // 8388608 B
  bf16*   t64  = (bf16*)(ws + 26214400);    // 2097152 B
  bf16*   fbuf = (bf16*)(ws + 28311552);    // 5242880 B
  bf16*   zbuf = (bf16*)(ws + 33554432);    // 4325376 B -> end ~36.1 MB

  k_sniff<<<1, 64, 0, stream>>>((const unsigned int*)d_in[0], flag);

  launch_prep<float>(0, flag, d_in, d_out, stream, xyz);
  launch_prep<bf16>(1, flag, d_in, d_out, stream, xyz);

  k_knn<<<dim3(NN / KQ, BB), 256, 0, stream>>>(xyz, idx);

  launch_rest<float>(0, flag, d_in, d_out, stream, xyz, idx, t512, t256, t64, fbuf, zbuf);
  launch_rest<bf16>(1, flag, d_in, d_out, stream, xyz, idx, t512, t256, t64, fbuf, zbuf);
}